// Round 8
// baseline (290.064 us; speedup 1.0000x reference)
//
#include <hip/hip_runtime.h>
#include <hip/hip_bf16.h>
#include <math.h>

#define T_TOKENS 8192
#define N_EXP    64
#define CAP      320   // floor(2 * 1.25 * 8192 / 64) = 320, even, > MIN_CAPACITY
#define ROWSZ    (N_EXP * CAP)           // 20480 floats per token row
#define ROWQ     (ROWSZ / 4)             // 5120 float4 per row
#define CBQ4     ((unsigned)(T_TOKENS) * (unsigned)ROWQ)   // 41,943,040 float4 in cb region

typedef float f32x4 __attribute__((ext_vector_type(4)));

// ---------------------------------------------------------------------------
// Kernel 1: per-token softmax + top-2. Four tokens per 64-lane wave:
// 16 lanes per token, each lane holds 4 experts (one float4 load).
// ---------------------------------------------------------------------------
__global__ __launch_bounds__(256) void moe_topk_kernel(
    const float* __restrict__ in,
    int* __restrict__ top1, int* __restrict__ top2,
    float2* __restrict__ wp)
{
    const int lane = threadIdx.x & 63;
    const int wv   = threadIdx.x >> 6;
    const int g    = lane >> 4;
    const int sub  = lane & 15;
    const int t    = blockIdx.x * 16 + wv * 4 + g;

    const float4 xv = ((const float4*)in)[(size_t)t * 16 + sub];
    const int b0 = sub * 4;

    // argmax, first-index tiebreak
    float v = xv.x; int idx = b0;
    if (xv.y > v) { v = xv.y; idx = b0 + 1; }
    if (xv.z > v) { v = xv.z; idx = b0 + 2; }
    if (xv.w > v) { v = xv.w; idx = b0 + 3; }
    #pragma unroll
    for (int off = 8; off; off >>= 1) {
        float vo = __shfl_xor(v, off);
        int   io = __shfl_xor(idx, off);
        if (vo > v || (vo == v && io < idx)) { v = vo; idx = io; }
    }
    const float m  = v;
    const int   i1 = idx;

    // softmax denominator
    float s = expf(xv.x - m) + expf(xv.y - m) + expf(xv.z - m) + expf(xv.w - m);
    #pragma unroll
    for (int off = 8; off; off >>= 1) s += __shfl_xor(s, off);

    // second argmax (exclude i1)
    const float c0 = (b0     == i1) ? -INFINITY : xv.x;
    const float c1v = (b0 + 1 == i1) ? -INFINITY : xv.y;
    const float c2v = (b0 + 2 == i1) ? -INFINITY : xv.z;
    const float c3v = (b0 + 3 == i1) ? -INFINITY : xv.w;
    float v2 = c0; int idx2 = b0;
    if (c1v > v2) { v2 = c1v; idx2 = b0 + 1; }
    if (c2v > v2) { v2 = c2v; idx2 = b0 + 2; }
    if (c3v > v2) { v2 = c3v; idx2 = b0 + 3; }
    #pragma unroll
    for (int off = 8; off; off >>= 1) {
        float vo = __shfl_xor(v2, off);
        int   io = __shfl_xor(idx2, off);
        if (vo > v2 || (vo == v2 && io < idx2)) { v2 = vo; idx2 = io; }
    }

    if (sub == 0) {
        top1[t] = i1;
        top2[t] = idx2;
        wp[t]   = make_float2(1.0f / s, expf(v2 - m) / s);
    }
}

// ---------------------------------------------------------------------------
// Kernel 2: one 1024-thread block per expert. Two-level parallel scan gives
// token-order cumsum ranks; emits packed slot c = e*CAP + r (or -1 if
// dropped) and used_capacity.
// ---------------------------------------------------------------------------
__global__ __launch_bounds__(1024) void moe_rank_kernel(
    const int* __restrict__ top1, const int* __restrict__ top2,
    int* __restrict__ c1, int* __restrict__ c2,
    float* __restrict__ out)
{
    const int e    = blockIdx.x;
    const int tid  = threadIdx.x;
    const int lane = tid & 63;
    const int wid  = tid >> 6;           // 16 waves

    __shared__ int wsA[16], wsB[16];

    // ---------------- pass 1: top1 ----------------
    const int4 a1 = ((const int4*)top1)[tid * 2];
    const int4 b1 = ((const int4*)top1)[tid * 2 + 1];
    const int m0 = (a1.x == e), m1 = (a1.y == e), m2 = (a1.z == e), m3 = (a1.w == e);
    const int m4 = (b1.x == e), m5 = (b1.y == e), m6 = (b1.z == e), m7 = (b1.w == e);
    const int cnt1 = m0 + m1 + m2 + m3 + m4 + m5 + m6 + m7;

    int sc = cnt1;
    #pragma unroll
    for (int off = 1; off < 64; off <<= 1) {
        int n = __shfl_up(sc, off);
        if (lane >= off) sc += n;
    }
    if (lane == 63) wsA[wid] = sc;
    __syncthreads();
    int wbase = 0, total1 = 0;
    #pragma unroll
    for (int w = 0; w < 16; ++w) {
        const int sv = wsA[w];
        if (w < wid) wbase += sv;
        total1 += sv;
    }
    {
        int r = wbase + sc - cnt1;
        const int t0 = tid * 8;
        #define RANK1(K, MK) \
            if (MK) { c1[t0 + K] = (r < CAP) ? (e * CAP + r) : -1; ++r; }
        RANK1(0, m0) RANK1(1, m1) RANK1(2, m2) RANK1(3, m3)
        RANK1(4, m4) RANK1(5, m5) RANK1(6, m6) RANK1(7, m7)
        #undef RANK1
    }

    // ---------------- pass 2: top2 (offset by total1) ----------------
    const int4 a2 = ((const int4*)top2)[tid * 2];
    const int4 b2 = ((const int4*)top2)[tid * 2 + 1];
    const int n0 = (a2.x == e), n1 = (a2.y == e), n2 = (a2.z == e), n3 = (a2.w == e);
    const int n4 = (b2.x == e), n5 = (b2.y == e), n6 = (b2.z == e), n7 = (b2.w == e);
    const int cnt2 = n0 + n1 + n2 + n3 + n4 + n5 + n6 + n7;

    int sc2 = cnt2;
    #pragma unroll
    for (int off = 1; off < 64; off <<= 1) {
        int n = __shfl_up(sc2, off);
        if (lane >= off) sc2 += n;
    }
    if (lane == 63) wsB[wid] = sc2;
    __syncthreads();
    int wbase2 = 0, total2 = 0;
    #pragma unroll
    for (int w = 0; w < 16; ++w) {
        const int sv = wsB[w];
        if (w < wid) wbase2 += sv;
        total2 += sv;
    }
    {
        int r = total1 + wbase2 + sc2 - cnt2;
        const int t0 = tid * 8;
        #define RANK2(K, NK) \
            if (NK) { c2[t0 + K] = (r < CAP) ? (e * CAP + r) : -1; ++r; }
        RANK2(0, n0) RANK2(1, n1) RANK2(2, n2) RANK2(3, n3)
        RANK2(4, n4) RANK2(5, n5) RANK2(6, n6) RANK2(7, n7)
        #undef RANK2
    }

    if (tid == 0) {
        const int kept1 = min(total1, CAP);
        const int kept2 = min(max(CAP - total1, 0), total2);
        out[e] = (float)(kept1 + kept2);
    }
}

// ---------------------------------------------------------------------------
// Kernel 3: fused zero+value writer with the rocclr-fill dispatch shape:
// one float4 store per thread, global-thread-id addressing so the write
// window slides linearly through memory as blocks dispatch in order.
// Covers cb_weight then sec_mask (83,886,080 float4 = 327,680 blocks x 256).
// Lookup data (c1/c2/wp) is wave-broadcast and L1-hot (row = 80 KB >> 1 KB
// per wave store).
// ---------------------------------------------------------------------------
__global__ __launch_bounds__(256) void moe_fill_kernel(
    const int* __restrict__ c1, const int* __restrict__ c2,
    const float2* __restrict__ wp,
    float* __restrict__ out)
{
    const unsigned gid = blockIdx.x * 256u + threadIdx.x;  // float4 idx in [cb|sec]
    const bool is_sec  = gid >= CBQ4;
    const unsigned rq  = is_sec ? (gid - CBQ4) : gid;
    const unsigned t   = rq / ROWQ;          // token (const-divide -> mul_hi)
    const unsigned p   = rq % ROWQ;          // float4 within row

    const int s1 = c1[t];
    const int s2 = c2[t];
    float va, vb;
    if (is_sec) { va = 1.0f; vb = 1.0f; }
    else        { const float2 w = wp[t]; va = w.x; vb = w.y; }

    const int base = (int)p * 4;
    f32x4 v;
    #pragma unroll
    for (int j = 0; j < 4; ++j) {
        const int pos = base + j;
        float x = 0.f;
        if (pos == s1) x += va;
        if (pos == s2) x += vb;
        v[j] = x;
    }
    ((f32x4*)(out + N_EXP))[gid] = v;
}

// ---------------------------------------------------------------------------
extern "C" void kernel_launch(void* const* d_in, const int* in_sizes, int n_in,
                              void* d_out, int out_size, void* d_ws, size_t ws_size,
                              hipStream_t stream) {
    const float* in  = (const float*)d_in[0];
    float*       out = (float*)d_out;

    // workspace: top1 | top2 | c1 | c2 (int[T] each) | wp (float2[T])
    int*    top1 = (int*)d_ws;
    int*    top2 = top1 + T_TOKENS;
    int*    c1   = top2 + T_TOKENS;
    int*    c2   = c1 + T_TOKENS;
    float2* wp   = (float2*)(c2 + T_TOKENS);

    moe_topk_kernel<<<T_TOKENS / 16, 256, 0, stream>>>(in, top1, top2, wp);
    moe_rank_kernel<<<N_EXP, 1024, 0, stream>>>(top1, top2, c1, c2, out);

    const unsigned nq4 = 2u * CBQ4;                 // 83,886,080 float4
    moe_fill_kernel<<<nq4 / 256u, 256, 0, stream>>>(c1, c2, wp, out);
}